// Round 3
// baseline (2645.182 us; speedup 1.0000x reference)
//
#include <hip/hip_runtime.h>
#include <float.h>

// Problem shape (fixed by setup_inputs): x[32768,512], embed[4096,512]
#define D 512
#define NPTS 32768
#define KCODES 4096
#define EPSV 1e-6f

// ---------------------------------------------------------------------------
// Bit-exact emulation of numpy fp32 pairwise sum of squares over a 512-row.
// numpy pairwise_sum: n=512 -> 256+256 -> 128-blocks; each 128-block uses 8
// stride-8 accumulator chains (16 elems each, ascending), combined as
// ((r0+r1)+(r2+r3))+((r4+r5)+(r6+r7)); blocks as ((b0+b1)+(b2+b3)).
// Balanced tree == xor-butterfly over 32 chains (fp32 add is commutative).
// One 64-lane wave handles 2 rows (lanes 0-31 / 32-63). 8 rows per block.
__device__ __forceinline__ float np_sumsq_512(const float* __restrict__ row, int l) {
    int b = l >> 3, j = l & 7;
    int base = b * 128 + j;
    float a = row[base];
    float r = __fmul_rn(a, a);
#pragma unroll
    for (int t = 1; t < 16; ++t) {
        float v = row[base + 8 * t];
        r = __fadd_rn(r, __fmul_rn(v, v));
    }
#pragma unroll
    for (int off = 1; off <= 16; off <<= 1)
        r = __fadd_rn(r, __shfl_xor(r, off));
    return r;  // all 32 lanes of the half hold the bit-exact numpy value
}

__global__ void xx_np_kernel(const float* __restrict__ x, float* __restrict__ xx_np) {
    int w = threadIdx.x >> 6, lane = threadIdx.x & 63;
    int half = lane >> 5, l = lane & 31;
    int p = blockIdx.x * 8 + w * 2 + half;
    float r = np_sumsq_512(x + (size_t)p * D, l);
    if (l == 0) xx_np[p] = r;
}

__global__ void ee_np_kernel(const float* __restrict__ emb, float* __restrict__ ee_np) {
    int w = threadIdx.x >> 6, lane = threadIdx.x & 63;
    int half = lane >> 5, l = lane & 31;
    int k = blockIdx.x * 8 + w * 2 + half;
    float r = np_sumsq_512(emb + (size_t)k * D, l);
    if (l == 0) ee_np[k] = r;
}

// ---------------------------------------------------------------------------
__global__ void init_ncs_kernel(const float* __restrict__ cs,
                                const float* __restrict__ decay_p,
                                float* __restrict__ ncs) {
    int i = blockIdx.x * 256 + threadIdx.x;
    if (i < KCODES) ncs[i] = cs[i] * decay_p[0];
}

__global__ void init_nea_kernel(const float* __restrict__ ea,
                                const float* __restrict__ decay_p,
                                float* __restrict__ nea) {
    int i = blockIdx.x * 256 + threadIdx.x;  // K*D = 2M threads
    nea[i] = ea[i] * decay_p[0];
}

// ---------------------------------------------------------------------------
// Fused fp32 GEMM + argmin candidate SCREEN (approximate; winner decided by
// the numpy-fp32-emulating rescore). Emits true-fp32-screen top-2 per
// (point, codebook-half) -> 4 candidates/point. A miss requires 2 codes
// within ~1e-4 of the winner in one half: P ~ 3e-2 dataset-wide.
__global__ __launch_bounds__(256, 1)
void argmin_kernel(const float* __restrict__ x, const float* __restrict__ emb,
                   const float* __restrict__ ee, int* __restrict__ cand) {
    __shared__ float As[16][128];  // [d][point]
    __shared__ float Bs[16][128];  // [d][code]

    const int tid = threadIdx.x;
    const int tx = tid & 15, ty = tid >> 4;
    const int n0 = blockIdx.x * 128;
    const int split = blockIdx.y;
    const int cbase = split * (KCODES / 2);

    float v1[8], v2[8];
    int   i1[8], i2[8];
#pragma unroll
    for (int i = 0; i < 8; ++i) { v1[i] = FLT_MAX; v2[i] = FLT_MAX; i1[i] = 0; i2[i] = 0; }

    float4 pa0, pa1, pb0, pb1;
    const int row0 = tid >> 2, quad = tid & 3;
    const int row1 = (tid + 256) >> 2;
    auto load_tiles = [&](int cc, int dk) {
        const float* ap = x + (size_t)(n0)*D + dk * 16 + quad * 4;
        pa0 = *(const float4*)(ap + (size_t)row0 * D);
        pa1 = *(const float4*)(ap + (size_t)row1 * D);
        const float* bp = emb + (size_t)(cbase + cc * 128) * D + dk * 16 + quad * 4;
        pb0 = *(const float4*)(bp + (size_t)row0 * D);
        pb1 = *(const float4*)(bp + (size_t)row1 * D);
    };
    load_tiles(0, 0);

    for (int cc = 0; cc < 16; ++cc) {             // 16 chunks of 128 codes
        float acc[8][8];
#pragma unroll
        for (int i = 0; i < 8; ++i)
#pragma unroll
            for (int j = 0; j < 8; ++j) acc[i][j] = 0.f;

        for (int dk = 0; dk < 32; ++dk) {         // D=512 in BK=16 steps
            float4 ca0 = pa0, ca1 = pa1, cb0 = pb0, cb1 = pb1;
            int ndk = (dk + 1) & 31;
            int ncc = (ndk == 0) ? ((cc + 1) & 15) : cc;   // wrap: values unused at end
            load_tiles(ncc, ndk);                  // issue next loads early

            __syncthreads();
            As[quad * 4 + 0][row0] = ca0.x; As[quad * 4 + 1][row0] = ca0.y;
            As[quad * 4 + 2][row0] = ca0.z; As[quad * 4 + 3][row0] = ca0.w;
            As[quad * 4 + 0][row1] = ca1.x; As[quad * 4 + 1][row1] = ca1.y;
            As[quad * 4 + 2][row1] = ca1.z; As[quad * 4 + 3][row1] = ca1.w;
            Bs[quad * 4 + 0][row0] = cb0.x; Bs[quad * 4 + 1][row0] = cb0.y;
            Bs[quad * 4 + 2][row0] = cb0.z; Bs[quad * 4 + 3][row0] = cb0.w;
            Bs[quad * 4 + 0][row1] = cb1.x; Bs[quad * 4 + 1][row1] = cb1.y;
            Bs[quad * 4 + 2][row1] = cb1.z; Bs[quad * 4 + 3][row1] = cb1.w;
            __syncthreads();

#pragma unroll
            for (int k = 0; k < 16; ++k) {
                float a[8], b[8];
                *(float4*)&a[0] = *(const float4*)&As[k][ty * 4];
                *(float4*)&a[4] = *(const float4*)&As[k][64 + ty * 4];
                *(float4*)&b[0] = *(const float4*)&Bs[k][tx * 4];
                *(float4*)&b[4] = *(const float4*)&Bs[k][64 + tx * 4];
#pragma unroll
                for (int i = 0; i < 8; ++i)
#pragma unroll
                    for (int j = 0; j < 8; ++j)
                        acc[i][j] = fmaf(a[i], b[j], acc[i][j]);
            }
        }

        // epilogue: screen score = ee[c] - 2*dot ; running per-lane top-2
        const int c0 = cbase + cc * 128;
        float eev[8];
#pragma unroll
        for (int j = 0; j < 8; ++j) {
            int col = c0 + ((j < 4) ? (tx * 4 + j) : (64 + tx * 4 + (j - 4)));
            eev[j] = ee[col];
        }
#pragma unroll
        for (int i = 0; i < 8; ++i)
#pragma unroll
            for (int j = 0; j < 8; ++j) {
                float s = fmaf(-2.0f, acc[i][j], eev[j]);
                int col = c0 + ((j < 4) ? (tx * 4 + j) : (64 + tx * 4 + (j - 4)));
                if (s < v1[i]) {
                    v2[i] = v1[i]; i2[i] = i1[i];
                    v1[i] = s;     i1[i] = col;
                } else if (s < v2[i]) {
                    v2[i] = s;     i2[i] = col;
                }
            }
    }

    // cross-lane (16-lane col group) TRUE top-2 merge per row
#pragma unroll
    for (int i = 0; i < 8; ++i) {
        float a1 = v1[i], a2 = v2[i];
        int   ai1 = i1[i], ai2 = i2[i];
#pragma unroll
        for (int off = 8; off >= 1; off >>= 1) {
            float o1 = __shfl_xor(a1, off); int oi1 = __shfl_xor(ai1, off);
            float o2 = __shfl_xor(a2, off); int oi2 = __shfl_xor(ai2, off);
            if (o1 < a1 || (o1 == a1 && oi1 < ai1)) {
                float nv2; int ni2;
                if (o2 < a1 || (o2 == a1 && oi2 < ai1)) { nv2 = o2; ni2 = oi2; }
                else                                     { nv2 = a1; ni2 = ai1; }
                a1 = o1; ai1 = oi1; a2 = nv2; ai2 = ni2;
            } else {
                if (o1 < a2 || (o1 == a2 && oi1 < ai2)) { a2 = o1; ai2 = oi1; }
            }
        }
        if (tx == 0) {
            int row = (i < 4) ? (ty * 4 + i) : (64 + ty * 4 + (i - 4));
            int point = n0 + row;
            cand[(split * 2 + 0) * NPTS + point] = ai1;
            cand[(split * 2 + 1) * NPTS + point] = ai2;
        }
    }
}

// ---------------------------------------------------------------------------
// Final selection emulating numpy fp32: d = fl32(fl32(xx - 2*fl32(dot)) + ee)
// with dot computed in fp64 (stands in for sgemm's fp32 result; both are
// within ~2e-7 of exact). Tie-break: lowest index (numpy argmin first-occ).
// One wave per point.
__global__ void rescore_kernel(const float* __restrict__ x, const float* __restrict__ emb,
                               const int* __restrict__ cand,
                               const float* __restrict__ xx_np,
                               const float* __restrict__ ee_np,
                               float* __restrict__ ind_f,
                               float* __restrict__ ncs, const float* __restrict__ decay_p) {
    int w = threadIdx.x >> 6, lane = threadIdx.x & 63;
    int n = blockIdx.x * 4 + w;
    float xxv = xx_np[n];
    float bestd = FLT_MAX; int bidx = 0x7fffffff;
#pragma unroll
    for (int c = 0; c < 4; ++c) {
        int k = cand[c * NPTS + n];
        double acc = 0.0;
#pragma unroll
        for (int i = 0; i < 8; ++i) {
            int d = lane + i * 64;
            acc += (double)emb[(size_t)k * D + d] * (double)x[(size_t)n * D + d];
        }
#pragma unroll
        for (int off = 32; off >= 1; off >>= 1) acc += __shfl_xor(acc, off);
        float mf = (float)acc;                 // fl32(dot)
        float t  = __fmul_rn(2.0f, mf);        // exact *2
        float u  = __fsub_rn(xxv, t);          // fl32(xx - t)   (no fma contraction)
        float dd = __fadd_rn(u, ee_np[k]);     // fl32(u + ee)
        if (dd < bestd || (dd == bestd && k < bidx)) { bestd = dd; bidx = k; }
    }
    if (lane == 0) {
        ind_f[n] = (float)bidx;
        atomicAdd(&ncs[bidx], 1.0f - decay_p[0]);
    }
}

// ---------------------------------------------------------------------------
// quantize[n] = embed[ind[n]] (old embed) ; nea[ind[n]] += x[n]*(1-decay)
__global__ void gather_scatter_kernel(const float* __restrict__ x,
                                      const float* __restrict__ emb,
                                      const float* __restrict__ ind_f,
                                      float* __restrict__ quant, float* __restrict__ nea,
                                      const float* __restrict__ decay_p) {
    int gid = blockIdx.x * 256 + threadIdx.x;   // NPTS * (D/4)
    int n = gid >> 7, dq = gid & 127;
    int k = (int)ind_f[n];
    float4 e4 = *(const float4*)(emb + (size_t)k * D + dq * 4);
    *(float4*)(quant + (size_t)n * D + dq * 4) = e4;
    float4 x4 = *(const float4*)(x + (size_t)n * D + dq * 4);
    float wgt = 1.0f - decay_p[0];
    float* base = nea + (size_t)k * D + dq * 4;
    atomicAdd(base + 0, x4.x * wgt);
    atomicAdd(base + 1, x4.y * wgt);
    atomicAdd(base + 2, x4.z * wgt);
    atomicAdd(base + 3, x4.w * wgt);
}

// ---------------------------------------------------------------------------
__global__ void total_kernel(const float* __restrict__ ncs, float* __restrict__ total) {
    __shared__ float sd[1024];
    int t = threadIdx.x;
    sd[t] = ncs[t] + ncs[t + 1024] + ncs[t + 2048] + ncs[t + 3072];
    __syncthreads();
    for (int st = 512; st > 0; st >>= 1) {
        if (t < st) sd[t] += sd[t + st];
        __syncthreads();
    }
    if (t == 0) total[0] = sd[0];
}

__global__ void new_embed_kernel(const float* __restrict__ nea, const float* __restrict__ ncs,
                                 const float* __restrict__ total, float* __restrict__ ne) {
    int i = blockIdx.x * 256 + threadIdx.x;   // K*D
    int k = i >> 9;
    float t = total[0];
    float sm = (ncs[k] + EPSV) / (t + EPSV * (float)KCODES) * t;
    ne[i] = nea[i] / sm;
}

// ---------------------------------------------------------------------------
extern "C" void kernel_launch(void* const* d_in, const int* in_sizes, int n_in,
                              void* d_out, int out_size, void* d_ws, size_t ws_size,
                              hipStream_t stream) {
    const float* x     = (const float*)d_in[0];
    const float* emb   = (const float*)d_in[1];
    const float* cs    = (const float*)d_in[2];
    const float* ea    = (const float*)d_in[3];
    const float* decay = (const float*)d_in[4];

    float* out   = (float*)d_out;
    float* quant = out;                               // NPTS*D
    float* ind_f = out + (size_t)NPTS * D;            // NPTS
    float* ncs   = ind_f + NPTS;                      // KCODES
    float* nea   = ncs + KCODES;                      // KCODES*D
    float* ne    = nea + (size_t)KCODES * D;          // KCODES*D

    float* ws    = (float*)d_ws;
    float* ee_np = ws;                                // KCODES floats
    float* xx_np = ws + KCODES;                       // NPTS floats
    int*   cand  = (int*)(xx_np + NPTS);              // 4*NPTS ints
    float* total = (float*)(cand + 4 * NPTS);         // 1 float

    hipLaunchKernelGGL(ee_np_kernel,    dim3(KCODES / 8),        dim3(256), 0, stream, emb, ee_np);
    hipLaunchKernelGGL(xx_np_kernel,    dim3(NPTS / 8),          dim3(256), 0, stream, x, xx_np);
    hipLaunchKernelGGL(init_ncs_kernel, dim3(KCODES / 256),      dim3(256), 0, stream, cs, decay, ncs);
    hipLaunchKernelGGL(init_nea_kernel, dim3(KCODES * (D / 256)), dim3(256), 0, stream, ea, decay, nea);
    hipLaunchKernelGGL(argmin_kernel,   dim3(NPTS / 128, 2),     dim3(256), 0, stream, x, emb, ee_np, cand);
    hipLaunchKernelGGL(rescore_kernel,  dim3(NPTS / 4),          dim3(256), 0, stream,
                       x, emb, cand, xx_np, ee_np, ind_f, ncs, decay);
    hipLaunchKernelGGL(gather_scatter_kernel, dim3(NPTS * (D / 4) / 256), dim3(256), 0, stream,
                       x, emb, ind_f, quant, nea, decay);
    hipLaunchKernelGGL(total_kernel,    dim3(1),                 dim3(1024), 0, stream, ncs, total);
    hipLaunchKernelGGL(new_embed_kernel, dim3(KCODES * (D / 256)), dim3(256), 0, stream, nea, ncs, total, ne);
}

// Round 4
// 712.409 us; speedup vs baseline: 3.7130x; 3.7130x over previous
//
#include <hip/hip_runtime.h>
#include <float.h>

// Problem shape (fixed by setup_inputs): x[32768,512], embed[4096,512]
#define D 512
#define NPTS 32768
#define KCODES 4096
#define EPSV 1e-6f

typedef __attribute__((ext_vector_type(8))) short short8;
typedef __attribute__((ext_vector_type(4))) float f32x4;
typedef unsigned short u16;
typedef __attribute__((ext_vector_type(8))) unsigned short u16x8;

// ---------------------------------------------------------------------------
// async global->LDS, 16B per lane (dest = wave-uniform base + lane*16)
__device__ __forceinline__ void async16(void* lds, const void* gl) {
    __builtin_amdgcn_global_load_lds(
        (const __attribute__((address_space(1))) unsigned int*)gl,
        (__attribute__((address_space(3))) unsigned int*)lds,
        16, 0, 0);
}

// fp32 -> bf16 round-to-nearest-even
__device__ __forceinline__ unsigned short f2bf(float f) {
    unsigned int u = __float_as_uint(f);
    u += 0x7fffu + ((u >> 16) & 1u);
    return (unsigned short)(u >> 16);
}

__global__ void cvt_bf16_kernel(const float* __restrict__ in, u16* __restrict__ out) {
    size_t i = (size_t)(blockIdx.x * 256 + threadIdx.x) * 8;
    float4 a = *(const float4*)(in + i);
    float4 b = *(const float4*)(in + i + 4);
    u16x8 r = { f2bf(a.x), f2bf(a.y), f2bf(a.z), f2bf(a.w),
                f2bf(b.x), f2bf(b.y), f2bf(b.z), f2bf(b.w) };
    *(u16x8*)(out + i) = r;
}

// ---------------------------------------------------------------------------
// Bit-exact emulation of numpy fp32 pairwise sum of squares over a 512-row.
// (verified passing in round 3 — do not change)
__device__ __forceinline__ float np_sumsq_512(const float* __restrict__ row, int l) {
    int b = l >> 3, j = l & 7;
    int base = b * 128 + j;
    float a = row[base];
    float r = __fmul_rn(a, a);
#pragma unroll
    for (int t = 1; t < 16; ++t) {
        float v = row[base + 8 * t];
        r = __fadd_rn(r, __fmul_rn(v, v));
    }
#pragma unroll
    for (int off = 1; off <= 16; off <<= 1)
        r = __fadd_rn(r, __shfl_xor(r, off));
    return r;
}

__global__ void xx_np_kernel(const float* __restrict__ x, float* __restrict__ xx_np) {
    int w = threadIdx.x >> 6, lane = threadIdx.x & 63;
    int hf = lane >> 5, l = lane & 31;
    int p = blockIdx.x * 8 + w * 2 + hf;
    float r = np_sumsq_512(x + (size_t)p * D, l);
    if (l == 0) xx_np[p] = r;
}

__global__ void ee_np_kernel(const float* __restrict__ emb, float* __restrict__ ee_np) {
    int w = threadIdx.x >> 6, lane = threadIdx.x & 63;
    int hf = lane >> 5, l = lane & 31;
    int k = blockIdx.x * 8 + w * 2 + hf;
    float r = np_sumsq_512(emb + (size_t)k * D, l);
    if (l == 0) ee_np[k] = r;
}

// ---------------------------------------------------------------------------
__global__ void init_ncs_kernel(const float* __restrict__ cs,
                                const float* __restrict__ decay_p,
                                float* __restrict__ ncs) {
    int i = blockIdx.x * 256 + threadIdx.x;
    if (i < KCODES) ncs[i] = cs[i] * decay_p[0];
}

__global__ void init_nea_kernel(const float* __restrict__ ea,
                                const float* __restrict__ decay_p,
                                float* __restrict__ nea) {
    int i = blockIdx.x * 256 + threadIdx.x;
    nea[i] = ea[i] * decay_p[0];
}

// ---------------------------------------------------------------------------
// bf16 MFMA screen: scores s[n][k] = ee[k] - 2*dot(x_n, e_k), exact screen
// top-4 per (point, codebook-half) emitted as (score, idx).
// Block: 256 thr = 4 waves (2x2 of 64x64 wave tiles), tile 128 pts x 128 codes,
// 16 chunks of 128 codes per half. BK=32, single-buffer 2-barrier K-loop,
// global_load_lds width 16. LDS chunk-XOR-swizzle p = kc ^ ((row>>2)&3) makes
// frag ds_read_b128 2-way-per-bank (free, m136).
#define INS4(s_, c_)  do {                                                  \
    bool l0 = (s_) < m0, l1 = (s_) < m1, l2 = (s_) < m2, l3 = (s_) < m3;    \
    m3 = l2 ? m2 : (l3 ? (s_) : m3);  q3 = l2 ? q2 : (l3 ? (c_) : q3);      \
    m2 = l1 ? m1 : (l2 ? (s_) : m2);  q2 = l1 ? q1 : (l2 ? (c_) : q2);      \
    m1 = l0 ? m0 : (l1 ? (s_) : m1);  q1 = l0 ? q0 : (l1 ? (c_) : q1);      \
    m0 = l0 ? (s_) : m0;              q0 = l0 ? (c_) : q0;                  \
} while (0)

__global__ __launch_bounds__(256, 2)
void screen_kernel(const u16* __restrict__ xb, const u16* __restrict__ eb,
                   const float* __restrict__ ee,
                   float* __restrict__ scr8, int* __restrict__ idx8) {
    __shared__ __align__(16) u16 Abuf[128 * 32];   // [row][k] 64B rows, swizzled
    __shared__ __align__(16) u16 Bbuf[128 * 32];
    __shared__ float s_scr[128][2][4];
    __shared__ int   s_idx[128][2][4];

    const int tid = threadIdx.x;
    const int w = tid >> 6, lane = tid & 63;
    const int wy = w >> 1, wx = w & 1;
    const int tx = lane & 15, g = lane >> 4;
    const int n0 = blockIdx.x * 128;
    const int hf = blockIdx.y;
    const int hbase = hf * 2048;

    // per-lane running top-2 per row-slot (fi*4+r)
    float v1[16], v2[16];
    int   i1[16], i2[16];
#pragma unroll
    for (int s = 0; s < 16; ++s) { v1[s] = FLT_MAX; v2[s] = FLT_MAX; i1[s] = 0; i2[s] = 0; }

    // staging lane constants: instr t covers rows [16t,16t+16); lane l ->
    // row 16t+(l>>2), physical 16B-chunk l&3 holds logical chunk (l&3)^(l>>4)
    const int kc = (lane & 3) ^ (lane >> 4);
    const int srow = lane >> 2;
    const int ta = 2 * w, tb = 2 * w + 1;

    for (int c = 0; c < 16; ++c) {
        const int c0 = hbase + c * 128;
        f32x4 acc[4][4];
#pragma unroll
        for (int fi = 0; fi < 4; ++fi)
#pragma unroll
            for (int fj = 0; fj < 4; ++fj) acc[fi][fj] = (f32x4){0.f, 0.f, 0.f, 0.f};

        for (int Kb = 0; Kb < 512; Kb += 32) {
            __syncthreads();   // prior frag reads done before overwrite
            async16(&Abuf[ta * 512], xb + (size_t)(n0 + 16 * ta + srow) * D + Kb + kc * 8);
            async16(&Abuf[tb * 512], xb + (size_t)(n0 + 16 * tb + srow) * D + Kb + kc * 8);
            async16(&Bbuf[ta * 512], eb + (size_t)(c0 + 16 * ta + srow) * D + Kb + kc * 8);
            async16(&Bbuf[tb * 512], eb + (size_t)(c0 + 16 * tb + srow) * D + Kb + kc * 8);
            __syncthreads();   // compiler emits vmcnt(0) drain before barrier

            short8 af[4], bf[4];
#pragma unroll
            for (int fi = 0; fi < 4; ++fi) {
                int row = wy * 64 + 16 * fi + tx;
                int ph = g ^ ((row >> 2) & 3);
                af[fi] = *(const short8*)&Abuf[row * 32 + ph * 8];
            }
#pragma unroll
            for (int fj = 0; fj < 4; ++fj) {
                int row = wx * 64 + 16 * fj + tx;
                int ph = g ^ ((row >> 2) & 3);
                bf[fj] = *(const short8*)&Bbuf[row * 32 + ph * 8];
            }
#pragma unroll
            for (int fi = 0; fi < 4; ++fi)
#pragma unroll
                for (int fj = 0; fj < 4; ++fj)
                    acc[fi][fj] = __builtin_amdgcn_mfma_f32_16x16x32_bf16(
                        af[fi], bf[fj], acc[fi][fj], 0, 0, 0);
        }

        // epilogue: s = ee[col] - 2*dot ; fold into per-lane top-2
#pragma unroll
        for (int fj = 0; fj < 4; ++fj) {
            int col = c0 + wx * 64 + 16 * fj + tx;
            float eev = ee[col];
#pragma unroll
            for (int fi = 0; fi < 4; ++fi)
#pragma unroll
                for (int r = 0; r < 4; ++r) {
                    float s = fmaf(-2.0f, acc[fi][fj][r], eev);
                    const int slot = fi * 4 + r;
                    bool b1 = s < v1[slot];
                    bool b2 = s < v2[slot];
                    float ov = v1[slot]; int oi = i1[slot];
                    v1[slot] = b1 ? s : ov;
                    i1[slot] = b1 ? col : oi;
                    v2[slot] = b1 ? ov : (b2 ? s : v2[slot]);
                    i2[slot] = b1 ? oi : (b2 ? col : i2[slot]);
                }
        }
    }

    // cross-lane: per row, exact top-4 over the wave's 64 cols
#pragma unroll
    for (int fi = 0; fi < 4; ++fi) {
#pragma unroll
        for (int r = 0; r < 4; ++r) {
            const int slot = fi * 4 + r;
            float m0 = v1[slot], m1 = v2[slot], m2 = FLT_MAX, m3 = FLT_MAX;
            int   q0 = i1[slot], q1 = i2[slot], q2 = 0, q3 = 0;
#pragma unroll
            for (int off = 1; off <= 8; off <<= 1) {
                float o0 = __shfl_xor(m0, off), o1 = __shfl_xor(m1, off);
                float o2 = __shfl_xor(m2, off), o3 = __shfl_xor(m3, off);
                int   p0 = __shfl_xor(q0, off), p1 = __shfl_xor(q1, off);
                int   p2 = __shfl_xor(q2, off), p3 = __shfl_xor(q3, off);
                INS4(o0, p0); INS4(o1, p1); INS4(o2, p2); INS4(o3, p3);
            }
            if (tx == 0) {
                int row = wy * 64 + 16 * fi + 4 * g + r;
                s_scr[row][wx][0] = m0; s_scr[row][wx][1] = m1;
                s_scr[row][wx][2] = m2; s_scr[row][wx][3] = m3;
                s_idx[row][wx][0] = q0; s_idx[row][wx][1] = q1;
                s_idx[row][wx][2] = q2; s_idx[row][wx][3] = q3;
            }
        }
    }
    __syncthreads();
    if (tid < 128) {
        float m0 = s_scr[tid][0][0], m1 = s_scr[tid][0][1],
              m2 = s_scr[tid][0][2], m3 = s_scr[tid][0][3];
        int   q0 = s_idx[tid][0][0], q1 = s_idx[tid][0][1],
              q2 = s_idx[tid][0][2], q3 = s_idx[tid][0][3];
#pragma unroll
        for (int q = 0; q < 4; ++q) INS4(s_scr[tid][1][q], s_idx[tid][1][q]);
        int pt = n0 + tid;
        scr8[(hf * 4 + 0) * NPTS + pt] = m0; idx8[(hf * 4 + 0) * NPTS + pt] = q0;
        scr8[(hf * 4 + 1) * NPTS + pt] = m1; idx8[(hf * 4 + 1) * NPTS + pt] = q1;
        scr8[(hf * 4 + 2) * NPTS + pt] = m2; idx8[(hf * 4 + 2) * NPTS + pt] = q2;
        scr8[(hf * 4 + 3) * NPTS + pt] = m3; idx8[(hf * 4 + 3) * NPTS + pt] = q3;
    }
}

// ---------------------------------------------------------------------------
// merge the two halves' top-4 into global screen top-4 per point
__global__ void merge8_kernel(const float* __restrict__ scr8, const int* __restrict__ idx8,
                              int* __restrict__ cand) {
    int n = blockIdx.x * 256 + threadIdx.x;
    float m0 = FLT_MAX, m1 = FLT_MAX, m2 = FLT_MAX, m3 = FLT_MAX;
    int   q0 = 0, q1 = 0, q2 = 0, q3 = 0;
#pragma unroll
    for (int c = 0; c < 8; ++c) {
        float s = scr8[c * NPTS + n];
        int   i = idx8[c * NPTS + n];
        INS4(s, i);
    }
    cand[0 * NPTS + n] = q0; cand[1 * NPTS + n] = q1;
    cand[2 * NPTS + n] = q2; cand[3 * NPTS + n] = q3;
}

// ---------------------------------------------------------------------------
// Final selection emulating numpy fp32 (verified passing in round 3 — unchanged)
__global__ void rescore_kernel(const float* __restrict__ x, const float* __restrict__ emb,
                               const int* __restrict__ cand,
                               const float* __restrict__ xx_np,
                               const float* __restrict__ ee_np,
                               float* __restrict__ ind_f,
                               float* __restrict__ ncs, const float* __restrict__ decay_p) {
    int w = threadIdx.x >> 6, lane = threadIdx.x & 63;
    int n = blockIdx.x * 4 + w;
    float xxv = xx_np[n];
    float bestd = FLT_MAX; int bidx = 0x7fffffff;
#pragma unroll
    for (int c = 0; c < 4; ++c) {
        int k = cand[c * NPTS + n];
        double acc = 0.0;
#pragma unroll
        for (int i = 0; i < 8; ++i) {
            int d = lane + i * 64;
            acc += (double)emb[(size_t)k * D + d] * (double)x[(size_t)n * D + d];
        }
#pragma unroll
        for (int off = 32; off >= 1; off >>= 1) acc += __shfl_xor(acc, off);
        float mf = (float)acc;
        float t  = __fmul_rn(2.0f, mf);
        float u  = __fsub_rn(xxv, t);
        float dd = __fadd_rn(u, ee_np[k]);
        if (dd < bestd || (dd == bestd && k < bidx)) { bestd = dd; bidx = k; }
    }
    if (lane == 0) {
        ind_f[n] = (float)bidx;
        atomicAdd(&ncs[bidx], 1.0f - decay_p[0]);
    }
}

// ---------------------------------------------------------------------------
__global__ void gather_scatter_kernel(const float* __restrict__ x,
                                      const float* __restrict__ emb,
                                      const float* __restrict__ ind_f,
                                      float* __restrict__ quant, float* __restrict__ nea,
                                      const float* __restrict__ decay_p) {
    int gid = blockIdx.x * 256 + threadIdx.x;   // NPTS * (D/4)
    int n = gid >> 7, dq = gid & 127;
    int k = (int)ind_f[n];
    float4 e4 = *(const float4*)(emb + (size_t)k * D + dq * 4);
    *(float4*)(quant + (size_t)n * D + dq * 4) = e4;
    float4 x4 = *(const float4*)(x + (size_t)n * D + dq * 4);
    float wgt = 1.0f - decay_p[0];
    float* base = nea + (size_t)k * D + dq * 4;
    atomicAdd(base + 0, x4.x * wgt);
    atomicAdd(base + 1, x4.y * wgt);
    atomicAdd(base + 2, x4.z * wgt);
    atomicAdd(base + 3, x4.w * wgt);
}

// ---------------------------------------------------------------------------
__global__ void total_kernel(const float* __restrict__ ncs, float* __restrict__ total) {
    __shared__ float sd[1024];
    int t = threadIdx.x;
    sd[t] = ncs[t] + ncs[t + 1024] + ncs[t + 2048] + ncs[t + 3072];
    __syncthreads();
    for (int st = 512; st > 0; st >>= 1) {
        if (t < st) sd[t] += sd[t + st];
        __syncthreads();
    }
    if (t == 0) total[0] = sd[0];
}

__global__ void new_embed_kernel(const float* __restrict__ nea, const float* __restrict__ ncs,
                                 const float* __restrict__ total, float* __restrict__ ne) {
    int i = blockIdx.x * 256 + threadIdx.x;   // K*D
    int k = i >> 9;
    float t = total[0];
    float sm = (ncs[k] + EPSV) / (t + EPSV * (float)KCODES) * t;
    ne[i] = nea[i] / sm;
}

// ---------------------------------------------------------------------------
extern "C" void kernel_launch(void* const* d_in, const int* in_sizes, int n_in,
                              void* d_out, int out_size, void* d_ws, size_t ws_size,
                              hipStream_t stream) {
    const float* x     = (const float*)d_in[0];
    const float* emb   = (const float*)d_in[1];
    const float* cs    = (const float*)d_in[2];
    const float* ea    = (const float*)d_in[3];
    const float* decay = (const float*)d_in[4];

    float* out   = (float*)d_out;
    float* quant = out;                               // NPTS*D
    float* ind_f = out + (size_t)NPTS * D;            // NPTS
    float* ncs   = ind_f + NPTS;                      // KCODES
    float* nea   = ncs + KCODES;                      // KCODES*D
    float* ne    = nea + (size_t)KCODES * D;          // KCODES*D

    float* ws    = (float*)d_ws;
    float* ee_np = ws;                                // KCODES
    float* xx_np = ws + KCODES;                       // NPTS
    float* scr8  = xx_np + NPTS;                      // 8*NPTS
    int*   idx8  = (int*)(scr8 + 8 * (size_t)NPTS);   // 8*NPTS
    int*   cand  = idx8 + 8 * (size_t)NPTS;           // 4*NPTS
    u16*   eb    = (u16*)(cand + 4 * (size_t)NPTS);   // KCODES*D bf16 (16B-aligned)
    float* total = (float*)(eb + (size_t)KCODES * D); // 1

    // bf16 x staged in the quant output region (overwritten at the end)
    u16* xb = (u16*)quant;

    hipLaunchKernelGGL(cvt_bf16_kernel, dim3(NPTS * D / 2048),   dim3(256), 0, stream, x, xb);
    hipLaunchKernelGGL(cvt_bf16_kernel, dim3(KCODES * D / 2048), dim3(256), 0, stream, emb, eb);
    hipLaunchKernelGGL(ee_np_kernel,    dim3(KCODES / 8),        dim3(256), 0, stream, emb, ee_np);
    hipLaunchKernelGGL(xx_np_kernel,    dim3(NPTS / 8),          dim3(256), 0, stream, x, xx_np);
    hipLaunchKernelGGL(init_ncs_kernel, dim3(KCODES / 256),      dim3(256), 0, stream, cs, decay, ncs);
    hipLaunchKernelGGL(init_nea_kernel, dim3(KCODES * (D / 256)), dim3(256), 0, stream, ea, decay, nea);
    hipLaunchKernelGGL(screen_kernel,   dim3(NPTS / 128, 2),     dim3(256), 0, stream,
                       xb, eb, ee_np, scr8, idx8);
    hipLaunchKernelGGL(merge8_kernel,   dim3(NPTS / 256),        dim3(256), 0, stream, scr8, idx8, cand);
    hipLaunchKernelGGL(rescore_kernel,  dim3(NPTS / 4),          dim3(256), 0, stream,
                       x, emb, cand, xx_np, ee_np, ind_f, ncs, decay);
    hipLaunchKernelGGL(gather_scatter_kernel, dim3(NPTS * (D / 4) / 256), dim3(256), 0, stream,
                       x, emb, ind_f, quant, nea, decay);
    hipLaunchKernelGGL(total_kernel,    dim3(1),                 dim3(1024), 0, stream, ncs, total);
    hipLaunchKernelGGL(new_embed_kernel, dim3(KCODES * (D / 256)), dim3(256), 0, stream, nea, ncs, total, ne);
}